// Round 5
// baseline (163.156 us; speedup 1.0000x reference)
//
#include <hip/hip_runtime.h>
#include <hip/hip_bf16.h>
#include <stdint.h>

// Problem constants: B=2, T=2048, C=1024, H=16, D=64
#define TT 2048
#define CC 1024
#define NH 16
#define HD 64
#define BT 4096          // B*T rows

typedef float f32x4 __attribute__((ext_vector_type(4)));
typedef __bf16 bf16x8 __attribute__((ext_vector_type(8)));
typedef __bf16 bf16x4 __attribute__((ext_vector_type(4)));

#define MFMA(a, b, c) __builtin_amdgcn_mfma_f32_16x16x32_bf16((a), (b), (c), 0, 0, 0)

__device__ __forceinline__ void gload16(const void* g, void* l) {
    __builtin_amdgcn_global_load_lds(
        (const __attribute__((address_space(1))) void*)g,
        (__attribute__((address_space(3))) void*)l,
        16, 0, 0);
}

// ---------------- fp32 -> bf16 convert (no transpose) ----------------
__global__ __launch_bounds__(256) void conv_f32_bf16(
    const float* __restrict__ in, __bf16* __restrict__ out, int n4) {
    int i = blockIdx.x * blockDim.x + threadIdx.x;
    int stride = gridDim.x * blockDim.x;
    for (; i < n4; i += stride) {
        float4 v = reinterpret_cast<const float4*>(in)[i];
        bf16x4 o;
        o.x = (__bf16)v.x; o.y = (__bf16)v.y; o.z = (__bf16)v.z; o.w = (__bf16)v.w;
        reinterpret_cast<bf16x4*>(out)[i] = o;
    }
}

// ---------------- fp32 [R][C] -> bf16 [C][R] transpose ----------------
__global__ __launch_bounds__(256) void transpose_f32_bf16(
    const float* __restrict__ in, __bf16* __restrict__ out, int R, int C) {
    __shared__ float tile[32][33];
    int c0 = blockIdx.x * 32, r0 = blockIdx.y * 32;
    int tx = threadIdx.x, ty = threadIdx.y;
#pragma unroll
    for (int j = 0; j < 32; j += 8)
        tile[ty + j][tx] = in[(size_t)(r0 + ty + j) * C + c0 + tx];
    __syncthreads();
#pragma unroll
    for (int j = 0; j < 32; j += 8)
        out[(size_t)(c0 + ty + j) * R + r0 + tx] = (__bf16)tile[tx][ty + j];
}

// ---------------- bf16 MFMA GEMM, 128x128 tile, BK=64 (m97 structure) ----
// C = A[M,K] * Bt[N,K]^T + bias. MODE 0: scatter q/k -> [B,H,T,D] bf16
// (q scaled by 0.125*log2e for exp2-softmax), v -> [B,H,D,T] bf16.
// MODE 1: fp32 output [M,N].
template <int MODE>
__global__ __launch_bounds__(256) void gemm128(
    const __bf16* __restrict__ A, const __bf16* __restrict__ Bt,
    const float* __restrict__ bias,
    __bf16* __restrict__ oq, __bf16* __restrict__ ok, __bf16* __restrict__ ov,
    float* __restrict__ of, int M, int N, int K) {
    __shared__ __align__(16) __bf16 As[128 * 64];
    __shared__ __align__(16) __bf16 Bs[128 * 64];
    const int tid = threadIdx.x;
    const int w = tid >> 6, lane = tid & 63;
    const int l15 = lane & 15, lg = lane >> 4;
    const int m0 = blockIdx.y * 128, n0 = blockIdx.x * 128;
    const int wr = w >> 1, wc = w & 1;

    const f32x4 zero4 = {0.f, 0.f, 0.f, 0.f};
    f32x4 acc[4][4];
#pragma unroll
    for (int m = 0; m < 4; ++m)
#pragma unroll
        for (int n = 0; n < 4; ++n) acc[m][n] = zero4;

    const char* Ab = (const char*)A;
    const char* Bb = (const char*)Bt;
    const size_t rowbytes = (size_t)K * 2;

    for (int kt = 0; kt < K; kt += 64) {
#pragma unroll
        for (int j = 0; j < 4; ++j) {
            int base = (w * 4 + j) * 1024;
            int d0 = base + lane * 16;
            int row = d0 >> 7;
            int colb = d0 & 127;
            int scolb = colb ^ ((row & 7) << 4);
            gload16(Ab + (size_t)(m0 + row) * rowbytes + (size_t)kt * 2 + scolb,
                    (char*)As + base);
            gload16(Bb + (size_t)(n0 + row) * rowbytes + (size_t)kt * 2 + scolb,
                    (char*)Bs + base);
        }
        __syncthreads();
#pragma unroll
        for (int kk = 0; kk < 2; ++kk) {
            bf16x8 af[4], bfr[4];
#pragma unroll
            for (int m = 0; m < 4; ++m) {
                int row = wr * 64 + m * 16 + l15;
                int colb = kk * 64 + lg * 16;
                af[m] = *(const bf16x8*)((const char*)As + row * 128 +
                                         (colb ^ ((row & 7) << 4)));
            }
#pragma unroll
            for (int n = 0; n < 4; ++n) {
                int row = wc * 64 + n * 16 + l15;
                int colb = kk * 64 + lg * 16;
                bfr[n] = *(const bf16x8*)((const char*)Bs + row * 128 +
                                          (colb ^ ((row & 7) << 4)));
            }
#pragma unroll
            for (int m = 0; m < 4; ++m)
#pragma unroll
                for (int n = 0; n < 4; ++n)
                    acc[m][n] = MFMA(af[m], bfr[n], acc[m][n]);
        }
        __syncthreads();
    }

    // epilogue. D layout: col = lane&15, row = (lane>>4)*4 + r  [verified m89/m91]
#pragma unroll
    for (int n = 0; n < 4; ++n) {
        int col = n0 + wc * 64 + n * 16 + l15;
        float bs = bias[col];
        if constexpr (MODE == 0) {
            int sec = col >> 10;          // 0=q 1=k 2=v
            int cc = col & 1023;
            int h = cc >> 6, d = cc & 63;
            if (sec == 2) {
                // V transposed: [B,H,D,T], pack 4 consecutive t per store
#pragma unroll
                for (int m = 0; m < 4; ++m) {
                    int rowb = m0 + wr * 64 + m * 16 + lg * 4;
                    int bb = rowb >> 11, t = rowb & 2047;
                    bf16x4 pk;
#pragma unroll
                    for (int r = 0; r < 4; ++r) pk[r] = (__bf16)(acc[m][n][r] + bs);
                    *(bf16x4*)&ov[((size_t)(bb * NH + h) * HD + d) * TT + t] = pk;
                }
            } else {
                __bf16* dst = (sec == 0) ? oq : ok;
                // fold softmax scale AND log2(e) into q so attn uses exp2
                float mult = (sec == 0) ? 0.125f * 1.44269504088896340736f : 1.0f;
#pragma unroll
                for (int m = 0; m < 4; ++m) {
                    int rowb = m0 + wr * 64 + m * 16 + lg * 4;
#pragma unroll
                    for (int r = 0; r < 4; ++r) {
                        int row = rowb + r;
                        int bb = row >> 11, t = row & 2047;
                        float val = (acc[m][n][r] + bs) * mult;
                        dst[((size_t)(bb * NH + h) * TT + t) * HD + d] = (__bf16)val;
                    }
                }
            }
        } else {
#pragma unroll
            for (int m = 0; m < 4; ++m) {
                int rowb = m0 + wr * 64 + m * 16 + lg * 4;
#pragma unroll
                for (int r = 0; r < 4; ++r) {
                    int row = rowb + r;
                    of[(size_t)row * N + col] = acc[m][n][r] + bs;
                }
            }
        }
    }
}

// ---------------- causal flash attention (dual-tile steps) ---------------
// QTILE=64 (4 waves x 16 q-rows), KVBLK=64. Block owns q-tiles (qp, 31-qp);
// iterates KV tiles 0..qtB ONCE, computing both q-tiles per staged tile when
// in range (t <= qtA). 512 blocks, ~49.4KB LDS -> 2 blocks/CU.
// q,k: [B,H,T,64] bf16 (q pre-scaled by 0.125*log2e). vt: [B,H,64,T] bf16.
__global__ __launch_bounds__(256) void attn_kernel(
    const __bf16* __restrict__ q, const __bf16* __restrict__ k,
    const __bf16* __restrict__ vt, __bf16* __restrict__ y) {
    __shared__ __align__(16) __bf16 Kb[2][64 * 64];    // [kv][d] 128B rows, XOR swz
    __shared__ __align__(16) __bf16 Vb[2][64 * 64];    // [d][kv] 128B rows, XOR swz
    __shared__ __align__(16) __bf16 Pl[4][2][16 * 68]; // per-wave per-tile [q][k]

    const int bh = blockIdx.y;
    const int qp = blockIdx.x;                 // 0..15 pair index
    const int tid = threadIdx.x, w = tid >> 6, lane = tid & 63;
    const int l15 = lane & 15, lg = lane >> 4;
    const char* kh = (const char*)(k + (size_t)bh * TT * HD);
    const char* vh = (const char*)(vt + (size_t)bh * HD * TT);
    const __bf16* qh = q + (size_t)bh * TT * HD;
    const int qtA = qp, qtB = 31 - qp;         // qtA < 16 <= qtB
    const int qbwA = qtA * 64 + w * 16, qbwB = qtB * 64 + w * 16;

    const f32x4 zero4 = {0.f, 0.f, 0.f, 0.f};
    float mrunA[4], lrunA[4], mrunB[4], lrunB[4];
    f32x4 oaccA[4], oaccB[4];
    bf16x8 qfA[2], qfB[2];

#pragma unroll
    for (int kk = 0; kk < 2; ++kk) {
        qfA[kk] = *(const bf16x8*)&qh[(size_t)(qbwA + l15) * HD + kk * 32 + lg * 8];
        qfB[kk] = *(const bf16x8*)&qh[(size_t)(qbwB + l15) * HD + kk * 32 + lg * 8];
    }
#pragma unroll
    for (int r = 0; r < 4; ++r) {
        mrunA[r] = -1e30f; lrunA[r] = 0.f;
        mrunB[r] = -1e30f; lrunB[r] = 0.f;
    }
#pragma unroll
    for (int f = 0; f < 4; ++f) { oaccA[f] = zero4; oaccB[f] = zero4; }

    auto stage = [&](int kvb, int buf) {
#pragma unroll
        for (int j = 0; j < 2; ++j) {
            int d0 = ((w * 2 + j) * 64 + lane) * 16;
            int row = d0 >> 7, colb = d0 & 127;
            int scolb = colb ^ ((row & 7) << 4);
            gload16(kh + (size_t)(kvb + row) * 128 + scolb, (char*)Kb[buf] + d0);
            gload16(vh + (size_t)row * (TT * 2) + (size_t)kvb * 2 + scolb,
                    (char*)Vb[buf] + d0);
        }
    };

    // one q-tile vs one staged KV tile (fully inlined; A/B calls interleave)
    auto tileStep = [&](int kb, int cur, const bf16x8 (&qf_)[2],
                        float (&mrun_)[4], float (&lrun_)[4], f32x4 (&oacc_)[4],
                        __bf16* Pw, int qbw_) {
        f32x4 s[4];
#pragma unroll
        for (int kf = 0; kf < 4; ++kf) s[kf] = zero4;
        __builtin_amdgcn_s_setprio(1);
#pragma unroll
        for (int kf = 0; kf < 4; ++kf) {
            int krow = kf * 16 + l15;
            const char* kr = (const char*)Kb[cur] + krow * 128;
            bf16x8 k0 = *(const bf16x8*)(kr + ((lg * 16) ^ ((krow & 7) << 4)));
            bf16x8 k1 = *(const bf16x8*)(kr + ((64 + lg * 16) ^ ((krow & 7) << 4)));
            s[kf] = MFMA(qf_[0], k0, s[kf]);
            s[kf] = MFMA(qf_[1], k1, s[kf]);
        }
        __builtin_amdgcn_s_setprio(0);
        // mask iff max col (kb+63) can exceed wave's MIN row (qbw_)
        if (kb + 63 > qbw_) {
#pragma unroll
            for (int kf = 0; kf < 4; ++kf)
#pragma unroll
                for (int r = 0; r < 4; ++r) {
                    int col = kb + kf * 16 + l15;
                    int rowq = qbw_ + lg * 4 + r;
                    if (col > rowq) s[kf][r] = -1e30f;
                }
        }
        float fac[4];
#pragma unroll
        for (int r = 0; r < 4; ++r) {
            float m_ = fmaxf(fmaxf(s[0][r], s[1][r]), fmaxf(s[2][r], s[3][r]));
#pragma unroll
            for (int off = 1; off < 16; off <<= 1)
                m_ = fmaxf(m_, __shfl_xor(m_, off));
            float mn = fmaxf(mrun_[r], m_);
            fac[r] = exp2f(mrun_[r] - mn);
            mrun_[r] = mn;
            float ss = 0.f;
#pragma unroll
            for (int kf = 0; kf < 4; ++kf) {
                float p = exp2f(s[kf][r] - mn);
                s[kf][r] = p;
                ss += p;
            }
#pragma unroll
            for (int off = 1; off < 16; off <<= 1)
                ss += __shfl_xor(ss, off);
            lrun_[r] = lrun_[r] * fac[r] + ss;
        }
#pragma unroll
        for (int f = 0; f < 4; ++f)
#pragma unroll
            for (int r = 0; r < 4; ++r) oacc_[f][r] *= fac[r];
#pragma unroll
        for (int kf = 0; kf < 4; ++kf)
#pragma unroll
            for (int r = 0; r < 4; ++r)
                Pw[(lg * 4 + r) * 68 + kf * 16 + l15] = (__bf16)s[kf][r];
        __builtin_amdgcn_s_setprio(1);
#pragma unroll
        for (int kq = 0; kq < 2; ++kq) {
            bf16x8 pa = *(const bf16x8*)&Pw[l15 * 68 + kq * 32 + lg * 8];
#pragma unroll
            for (int f = 0; f < 4; ++f) {
                int vrow = f * 16 + l15;
                bf16x8 vf = *(const bf16x8*)((const char*)Vb[cur] + vrow * 128 +
                                ((kq * 64 + lg * 16) ^ ((vrow & 7) << 4)));
                oacc_[f] = MFMA(pa, vf, oacc_[f]);
            }
        }
        __builtin_amdgcn_s_setprio(0);
    };

    auto writeO = [&](float (&lrun_)[4], f32x4 (&oacc_)[4], int qbw_) {
        const int b = bh >> 4, h = bh & 15;
#pragma unroll
        for (int f = 0; f < 4; ++f)
#pragma unroll
            for (int r = 0; r < 4; ++r) {
                int t = qbw_ + lg * 4 + r;
                float val = oacc_[f][r] / lrun_[r];
                y[(size_t)(b * TT + t) * CC + h * 64 + f * 16 + l15] = (__bf16)val;
            }
    };

    stage(0, 0);
    __syncthreads();

    for (int t = 0; t <= qtB; ++t) {
        const int cur = t & 1;
        if (t < qtB) stage((t + 1) * 64, cur ^ 1);
        const int kb = t * 64;
        if (t <= qtA) {
            tileStep(kb, cur, qfB, mrunB, lrunB, oaccB, &Pl[w][0][0], qbwB);
            tileStep(kb, cur, qfA, mrunA, lrunA, oaccA, &Pl[w][1][0], qbwA);
        } else {
            tileStep(kb, cur, qfB, mrunB, lrunB, oaccB, &Pl[w][0][0], qbwB);
        }
        __syncthreads();
    }
    writeO(lrunA, oaccA, qbwA);
    writeO(lrunB, oaccB, qbwB);
}

extern "C" void kernel_launch(void* const* d_in, const int* in_sizes, int n_in,
                              void* d_out, int out_size, void* d_ws, size_t ws_size,
                              hipStream_t stream) {
    const float* x      = (const float*)d_in[0];
    const float* w_attn = (const float*)d_in[1];
    const float* b_attn = (const float*)d_in[2];
    const float* w_proj = (const float*)d_in[3];
    const float* b_proj = (const float*)d_in[4];
    float* out = (float*)d_out;

    char* ws = (char*)d_ws;
    size_t off = 0;
    auto alloc = [&](size_t bytes) {
        char* p = ws + off;
        off += (bytes + 255) & ~(size_t)255;
        return p;
    };
    __bf16* xb   = (__bf16*)alloc((size_t)BT * CC * 2);
    __bf16* watb = (__bf16*)alloc((size_t)3 * CC * CC * 2);
    __bf16* wptb = (__bf16*)alloc((size_t)CC * CC * 2);
    __bf16* qb   = (__bf16*)alloc((size_t)BT * CC * 2);
    __bf16* kbuf = (__bf16*)alloc((size_t)BT * CC * 2);
    __bf16* vtb  = (__bf16*)alloc((size_t)BT * CC * 2);  // [B,H,D,T]
    __bf16* yb   = (__bf16*)alloc((size_t)BT * CC * 2);

    conv_f32_bf16<<<1024, 256, 0, stream>>>(x, xb, BT * CC / 4);
    transpose_f32_bf16<<<dim3(3 * CC / 32, CC / 32), dim3(32, 8), 0, stream>>>(
        w_attn, watb, CC, 3 * CC);
    transpose_f32_bf16<<<dim3(CC / 32, CC / 32), dim3(32, 8), 0, stream>>>(
        w_proj, wptb, CC, CC);

    gemm128<0><<<dim3(3 * CC / 128, BT / 128), 256, 0, stream>>>(
        xb, watb, b_attn, qb, kbuf, vtb, nullptr, BT, 3 * CC, CC);

    attn_kernel<<<dim3(16, 2 * NH), 256, 0, stream>>>(qb, kbuf, vtb, yb);

    gemm128<1><<<dim3(CC / 128, BT / 128), 256, 0, stream>>>(
        yb, wptb, b_proj, nullptr, nullptr, nullptr, out, BT, CC, CC);
}

// Round 6
// 127.886 us; speedup vs baseline: 1.2758x; 1.2758x over previous
//
#include <hip/hip_runtime.h>
#include <hip/hip_bf16.h>
#include <stdint.h>

// Problem constants: B=2, T=2048, C=1024, H=16, D=64
#define TT 2048
#define CC 1024
#define NH 16
#define HD 64
#define BT 4096          // B*T rows

typedef float f32x4 __attribute__((ext_vector_type(4)));
typedef __bf16 bf16x8 __attribute__((ext_vector_type(8)));
typedef __bf16 bf16x4 __attribute__((ext_vector_type(4)));

#define MFMA(a, b, c) __builtin_amdgcn_mfma_f32_16x16x32_bf16((a), (b), (c), 0, 0, 0)

__device__ __forceinline__ void gload16(const void* g, void* l) {
    __builtin_amdgcn_global_load_lds(
        (const __attribute__((address_space(1))) void*)g,
        (__attribute__((address_space(3))) void*)l,
        16, 0, 0);
}

// ---------------- fp32 -> bf16 convert (no transpose) ----------------
__global__ __launch_bounds__(256) void conv_f32_bf16(
    const float* __restrict__ in, __bf16* __restrict__ out, int n4) {
    int i = blockIdx.x * blockDim.x + threadIdx.x;
    int stride = gridDim.x * blockDim.x;
    for (; i < n4; i += stride) {
        float4 v = reinterpret_cast<const float4*>(in)[i];
        bf16x4 o;
        o.x = (__bf16)v.x; o.y = (__bf16)v.y; o.z = (__bf16)v.z; o.w = (__bf16)v.w;
        reinterpret_cast<bf16x4*>(out)[i] = o;
    }
}

// ---------------- fp32 [R][C] -> bf16 [C][R] transpose ----------------
__global__ __launch_bounds__(256) void transpose_f32_bf16(
    const float* __restrict__ in, __bf16* __restrict__ out, int R, int C) {
    __shared__ float tile[32][33];
    int c0 = blockIdx.x * 32, r0 = blockIdx.y * 32;
    int tx = threadIdx.x, ty = threadIdx.y;
#pragma unroll
    for (int j = 0; j < 32; j += 8)
        tile[ty + j][tx] = in[(size_t)(r0 + ty + j) * C + c0 + tx];
    __syncthreads();
#pragma unroll
    for (int j = 0; j < 32; j += 8)
        out[(size_t)(c0 + ty + j) * R + r0 + tx] = (__bf16)tile[tx][ty + j];
}

// ---------------- bf16 MFMA GEMM, 128x128 tile, BK=64 (m97 structure) ----
// C = A[M,K] * Bt[N,K]^T + bias. MODE 0: scatter q/k -> [B,H,T,D] bf16
// (q scaled by 0.125*log2e for exp2-softmax), v -> [B,H,D,T] bf16.
// MODE 1: fp32 output [M,N].
template <int MODE>
__global__ __launch_bounds__(256) void gemm128(
    const __bf16* __restrict__ A, const __bf16* __restrict__ Bt,
    const float* __restrict__ bias,
    __bf16* __restrict__ oq, __bf16* __restrict__ ok, __bf16* __restrict__ ov,
    float* __restrict__ of, int M, int N, int K) {
    __shared__ __align__(16) __bf16 As[128 * 64];
    __shared__ __align__(16) __bf16 Bs[128 * 64];
    const int tid = threadIdx.x;
    const int w = tid >> 6, lane = tid & 63;
    const int l15 = lane & 15, lg = lane >> 4;
    const int m0 = blockIdx.y * 128, n0 = blockIdx.x * 128;
    const int wr = w >> 1, wc = w & 1;

    const f32x4 zero4 = {0.f, 0.f, 0.f, 0.f};
    f32x4 acc[4][4];
#pragma unroll
    for (int m = 0; m < 4; ++m)
#pragma unroll
        for (int n = 0; n < 4; ++n) acc[m][n] = zero4;

    const char* Ab = (const char*)A;
    const char* Bb = (const char*)Bt;
    const size_t rowbytes = (size_t)K * 2;

    for (int kt = 0; kt < K; kt += 64) {
#pragma unroll
        for (int j = 0; j < 4; ++j) {
            int base = (w * 4 + j) * 1024;
            int d0 = base + lane * 16;
            int row = d0 >> 7;
            int colb = d0 & 127;
            int scolb = colb ^ ((row & 7) << 4);
            gload16(Ab + (size_t)(m0 + row) * rowbytes + (size_t)kt * 2 + scolb,
                    (char*)As + base);
            gload16(Bb + (size_t)(n0 + row) * rowbytes + (size_t)kt * 2 + scolb,
                    (char*)Bs + base);
        }
        __syncthreads();
#pragma unroll
        for (int kk = 0; kk < 2; ++kk) {
            bf16x8 af[4], bfr[4];
#pragma unroll
            for (int m = 0; m < 4; ++m) {
                int row = wr * 64 + m * 16 + l15;
                int colb = kk * 64 + lg * 16;
                af[m] = *(const bf16x8*)((const char*)As + row * 128 +
                                         (colb ^ ((row & 7) << 4)));
            }
#pragma unroll
            for (int n = 0; n < 4; ++n) {
                int row = wc * 64 + n * 16 + l15;
                int colb = kk * 64 + lg * 16;
                bfr[n] = *(const bf16x8*)((const char*)Bs + row * 128 +
                                          (colb ^ ((row & 7) << 4)));
            }
#pragma unroll
            for (int m = 0; m < 4; ++m)
#pragma unroll
                for (int n = 0; n < 4; ++n)
                    acc[m][n] = MFMA(af[m], bfr[n], acc[m][n]);
        }
        __syncthreads();
    }

    // epilogue. D layout: col = lane&15, row = (lane>>4)*4 + r  [verified m89/m91]
#pragma unroll
    for (int n = 0; n < 4; ++n) {
        int col = n0 + wc * 64 + n * 16 + l15;
        float bs = bias[col];
        if constexpr (MODE == 0) {
            int sec = col >> 10;          // 0=q 1=k 2=v
            int cc = col & 1023;
            int h = cc >> 6, d = cc & 63;
            if (sec == 2) {
                // V transposed: [B,H,D,T], pack 4 consecutive t per store
#pragma unroll
                for (int m = 0; m < 4; ++m) {
                    int rowb = m0 + wr * 64 + m * 16 + lg * 4;
                    int bb = rowb >> 11, t = rowb & 2047;
                    bf16x4 pk;
#pragma unroll
                    for (int r = 0; r < 4; ++r) pk[r] = (__bf16)(acc[m][n][r] + bs);
                    *(bf16x4*)&ov[((size_t)(bb * NH + h) * HD + d) * TT + t] = pk;
                }
            } else {
                __bf16* dst = (sec == 0) ? oq : ok;
                // fold softmax scale AND log2(e) into q so attn uses exp2
                float mult = (sec == 0) ? 0.125f * 1.44269504088896340736f : 1.0f;
#pragma unroll
                for (int m = 0; m < 4; ++m) {
                    int rowb = m0 + wr * 64 + m * 16 + lg * 4;
#pragma unroll
                    for (int r = 0; r < 4; ++r) {
                        int row = rowb + r;
                        int bb = row >> 11, t = row & 2047;
                        float val = (acc[m][n][r] + bs) * mult;
                        dst[((size_t)(bb * NH + h) * TT + t) * HD + d] = (__bf16)val;
                    }
                }
            }
        } else {
#pragma unroll
            for (int m = 0; m < 4; ++m) {
                int rowb = m0 + wr * 64 + m * 16 + lg * 4;
#pragma unroll
                for (int r = 0; r < 4; ++r) {
                    int row = rowb + r;
                    of[(size_t)row * N + col] = acc[m][n][r] + bs;
                }
            }
        }
    }
}

// ---------------- causal flash attention (swapped-operand softmax) -------
// QTILE=64 (4 waves x 16 q-rows), KVBLK=64, paired q-tiles (qt, 31-qt):
// 512 uniform blocks of 33 steps, ~41KB LDS -> 2+ blocks/CU.
// Swapped MFMA order: S^T = mfma(K,Q) puts q on l15 -> softmax state is
// per-lane scalar; k-reduce = in-lane tree + 2 shfl_xor (was 32 shfl/step).
// q,k: [B,H,T,64] bf16 (q pre-scaled by 0.125*log2e). vt: [B,H,64,T] bf16.
__global__ __launch_bounds__(256) void attn_kernel(
    const __bf16* __restrict__ q, const __bf16* __restrict__ k,
    const __bf16* __restrict__ vt, __bf16* __restrict__ y) {
    __shared__ __align__(16) __bf16 Kb[2][64 * 64];   // [kv][d] 128B rows, XOR swz
    __shared__ __align__(16) __bf16 Vb[2][64 * 64];   // [d][kv] 128B rows, XOR swz
    __shared__ __align__(16) __bf16 Pl[4][16 * 72];   // per-wave P^T as [q][k]

    const int bh = blockIdx.y;
    const int qp = blockIdx.x;                 // 0..15 pair index
    const int tid = threadIdx.x, w = tid >> 6, lane = tid & 63;
    const int l15 = lane & 15, lg = lane >> 4;
    const char* kh = (const char*)(k + (size_t)bh * TT * HD);
    const char* vh = (const char*)(vt + (size_t)bh * HD * TT);
    const __bf16* qh = q + (size_t)bh * TT * HD;
    const int qtA = qp, qtB = 31 - qp;
    const int nA = qtA + 1, ntot = nA + (qtB + 1);   // == 33

    const f32x4 zero4 = {0.f, 0.f, 0.f, 0.f};
    float mrun, lrun;
    f32x4 oacc[4];        // O^T: col=q=l15, row d = f*16 + lg*4 + r
    bf16x8 qf[2];
    int qbw = 0;

    auto stage = [&](int kvb, int buf) {
#pragma unroll
        for (int j = 0; j < 2; ++j) {
            int d0 = ((w * 2 + j) * 64 + lane) * 16;
            int row = d0 >> 7, colb = d0 & 127;
            int scolb = colb ^ ((row & 7) << 4);
            // K tile: rows kv (128B each)
            gload16(kh + (size_t)(kvb + row) * 128 + scolb, (char*)Kb[buf] + d0);
            // V^T tile: rows d (4096B each), cols kv (128B slice)
            gload16(vh + (size_t)row * (TT * 2) + (size_t)kvb * 2 + scolb,
                    (char*)Vb[buf] + d0);
        }
    };

    auto initQ = [&](int qt) {
        qbw = qt * 64 + w * 16;
#pragma unroll
        for (int kk = 0; kk < 2; ++kk)
            qf[kk] = *(const bf16x8*)&qh[(size_t)(qbw + l15) * HD + kk * 32 + lg * 8];
        mrun = -1e30f; lrun = 0.f;
#pragma unroll
        for (int f = 0; f < 4; ++f) oacc[f] = zero4;
    };

    auto writeO = [&]() {
        const int b = bh >> 4, h = bh & 15;
        float inv = 1.0f / lrun;
#pragma unroll
        for (int f = 0; f < 4; ++f) {
            bf16x4 pk;
#pragma unroll
            for (int r = 0; r < 4; ++r) pk[r] = (__bf16)(oacc[f][r] * inv);
            *(bf16x4*)&y[(size_t)(b * TT + qbw + l15) * CC + h * 64 + f * 16 +
                         lg * 4] = pk;
        }
    };

    stage(0, 0);
    initQ(qtA);
    __syncthreads();

    for (int g = 0; g < ntot; ++g) {
        const int cur = g & 1;
        if (g + 1 < ntot)
            stage((g + 1 < nA ? g + 1 : g + 1 - nA) * 64, cur ^ 1);
        const int kb = (g < nA ? g : g - nA) * 64;

        // ---- S^T = K Q^T ---- (col=q=l15, row k = kf*16 + lg*4 + r)
        f32x4 s[4];
#pragma unroll
        for (int kf = 0; kf < 4; ++kf) s[kf] = zero4;
        __builtin_amdgcn_s_setprio(1);
#pragma unroll
        for (int kf = 0; kf < 4; ++kf) {
            int krow = kf * 16 + l15;
            const char* kr = (const char*)Kb[cur] + krow * 128;
            bf16x8 k0 = *(const bf16x8*)(kr + ((lg * 16) ^ ((krow & 7) << 4)));
            bf16x8 k1 = *(const bf16x8*)(kr + ((64 + lg * 16) ^ ((krow & 7) << 4)));
            s[kf] = MFMA(k0, qf[0], s[kf]);
            s[kf] = MFMA(k1, qf[1], s[kf]);
        }
        __builtin_amdgcn_s_setprio(0);
        // mask iff max k (kb+63) can exceed wave's MIN q (qbw)
        const int qq = qbw + l15;
        if (kb + 63 > qbw) {
#pragma unroll
            for (int kf = 0; kf < 4; ++kf)
#pragma unroll
                for (int r = 0; r < 4; ++r) {
                    int kk_ = kb + kf * 16 + lg * 4 + r;
                    if (kk_ > qq) s[kf][r] = -1e30f;
                }
        }
        // ---- online softmax (per-lane q; in-lane k-reduce + 2 shfl) ----
        f32x4 m01, m23;
#pragma unroll
        for (int r = 0; r < 4; ++r) {
            m01[r] = fmaxf(s[0][r], s[1][r]);
            m23[r] = fmaxf(s[2][r], s[3][r]);
        }
        float m_ = fmaxf(fmaxf(fmaxf(m01[0], m01[1]), fmaxf(m01[2], m01[3])),
                         fmaxf(fmaxf(m23[0], m23[1]), fmaxf(m23[2], m23[3])));
        m_ = fmaxf(m_, __shfl_xor(m_, 16));
        m_ = fmaxf(m_, __shfl_xor(m_, 32));
        float mn = fmaxf(mrun, m_);
        float fac = exp2f(mrun - mn);
        mrun = mn;
        float ss = 0.f;
#pragma unroll
        for (int kf = 0; kf < 4; ++kf)
#pragma unroll
            for (int r = 0; r < 4; ++r) {
                float p = exp2f(s[kf][r] - mn);
                s[kf][r] = p;
                ss += p;
            }
        ss += __shfl_xor(ss, 16);
        ss += __shfl_xor(ss, 32);
        lrun = lrun * fac + ss;
#pragma unroll
        for (int f = 0; f < 4; ++f)
#pragma unroll
            for (int r = 0; r < 4; ++r) oacc[f][r] *= fac;
        // ---- P^T -> LDS (packed b64: r=0..3 are contiguous k) ----
#pragma unroll
        for (int kf = 0; kf < 4; ++kf) {
            bf16x4 pk;
#pragma unroll
            for (int r = 0; r < 4; ++r) pk[r] = (__bf16)s[kf][r];
            *(bf16x4*)&Pl[w][l15 * 72 + kf * 16 + lg * 4] = pk;
        }
        // ---- O^T += V^T P ---- (A=V^T rows d=l15, B=P^T cols q=l15)
        __builtin_amdgcn_s_setprio(1);
#pragma unroll
        for (int kq = 0; kq < 2; ++kq) {
            bf16x8 pfrag = *(const bf16x8*)&Pl[w][l15 * 72 + kq * 32 + lg * 8];
#pragma unroll
            for (int f = 0; f < 4; ++f) {
                int vrow = f * 16 + l15;
                bf16x8 vf = *(const bf16x8*)((const char*)Vb[cur] + vrow * 128 +
                                ((kq * 64 + lg * 16) ^ ((vrow & 7) << 4)));
                oacc[f] = MFMA(vf, pfrag, oacc[f]);
            }
        }
        __builtin_amdgcn_s_setprio(0);
        __syncthreads();
        if (g == nA - 1) { writeO(); initQ(qtB); }
    }
    writeO();
}

extern "C" void kernel_launch(void* const* d_in, const int* in_sizes, int n_in,
                              void* d_out, int out_size, void* d_ws, size_t ws_size,
                              hipStream_t stream) {
    const float* x      = (const float*)d_in[0];
    const float* w_attn = (const float*)d_in[1];
    const float* b_attn = (const float*)d_in[2];
    const float* w_proj = (const float*)d_in[3];
    const float* b_proj = (const float*)d_in[4];
    float* out = (float*)d_out;

    char* ws = (char*)d_ws;
    size_t off = 0;
    auto alloc = [&](size_t bytes) {
        char* p = ws + off;
        off += (bytes + 255) & ~(size_t)255;
        return p;
    };
    __bf16* xb   = (__bf16*)alloc((size_t)BT * CC * 2);
    __bf16* watb = (__bf16*)alloc((size_t)3 * CC * CC * 2);
    __bf16* wptb = (__bf16*)alloc((size_t)CC * CC * 2);
    __bf16* qb   = (__bf16*)alloc((size_t)BT * CC * 2);
    __bf16* kbuf = (__bf16*)alloc((size_t)BT * CC * 2);
    __bf16* vtb  = (__bf16*)alloc((size_t)BT * CC * 2);  // [B,H,D,T]
    __bf16* yb   = (__bf16*)alloc((size_t)BT * CC * 2);

    conv_f32_bf16<<<1024, 256, 0, stream>>>(x, xb, BT * CC / 4);
    transpose_f32_bf16<<<dim3(3 * CC / 32, CC / 32), dim3(32, 8), 0, stream>>>(
        w_attn, watb, CC, 3 * CC);
    transpose_f32_bf16<<<dim3(CC / 32, CC / 32), dim3(32, 8), 0, stream>>>(
        w_proj, wptb, CC, CC);

    gemm128<0><<<dim3(3 * CC / 128, BT / 128), 256, 0, stream>>>(
        xb, watb, b_attn, qb, kbuf, vtb, nullptr, BT, 3 * CC, CC);

    attn_kernel<<<dim3(16, 2 * NH), 256, 0, stream>>>(qb, kbuf, vtb, yb);

    gemm128<1><<<dim3(CC / 128, BT / 128), 256, 0, stream>>>(
        yb, wptb, b_proj, nullptr, nullptr, nullptr, out, BT, CC, CC);
}

// Round 7
// 123.400 us; speedup vs baseline: 1.3222x; 1.0364x over previous
//
#include <hip/hip_runtime.h>
#include <hip/hip_bf16.h>
#include <stdint.h>

// Problem constants: B=2, T=2048, C=1024, H=16, D=64
#define TT 2048
#define CC 1024
#define NH 16
#define HD 64
#define BT 4096          // B*T rows

typedef float f32x4 __attribute__((ext_vector_type(4)));
typedef __bf16 bf16x8 __attribute__((ext_vector_type(8)));
typedef __bf16 bf16x4 __attribute__((ext_vector_type(4)));

#define MFMA(a, b, c) __builtin_amdgcn_mfma_f32_16x16x32_bf16((a), (b), (c), 0, 0, 0)

__device__ __forceinline__ void gload16(const void* g, void* l) {
    __builtin_amdgcn_global_load_lds(
        (const __attribute__((address_space(1))) void*)g,
        (__attribute__((address_space(3))) void*)l,
        16, 0, 0);
}

// ---------------- fp32 -> bf16 convert (no transpose) ----------------
__global__ __launch_bounds__(256) void conv_f32_bf16(
    const float* __restrict__ in, __bf16* __restrict__ out, int n4) {
    int i = blockIdx.x * blockDim.x + threadIdx.x;
    int stride = gridDim.x * blockDim.x;
    for (; i < n4; i += stride) {
        float4 v = reinterpret_cast<const float4*>(in)[i];
        bf16x4 o;
        o.x = (__bf16)v.x; o.y = (__bf16)v.y; o.z = (__bf16)v.z; o.w = (__bf16)v.w;
        reinterpret_cast<bf16x4*>(out)[i] = o;
    }
}

// ---------------- fp32 [R][C] -> bf16 [C][R] transpose ----------------
__global__ __launch_bounds__(256) void transpose_f32_bf16(
    const float* __restrict__ in, __bf16* __restrict__ out, int R, int C) {
    __shared__ float tile[32][33];
    int c0 = blockIdx.x * 32, r0 = blockIdx.y * 32;
    int tx = threadIdx.x, ty = threadIdx.y;
#pragma unroll
    for (int j = 0; j < 32; j += 8)
        tile[ty + j][tx] = in[(size_t)(r0 + ty + j) * C + c0 + tx];
    __syncthreads();
#pragma unroll
    for (int j = 0; j < 32; j += 8)
        out[(size_t)(c0 + ty + j) * R + r0 + tx] = (__bf16)tile[tx][ty + j];
}

// ---------------- bf16 MFMA GEMM, 128x128 tile, BK=64 (m97 structure) ----
// C = A[M,K] * Bt[N,K]^T + bias. MODE 0: scatter q/k -> [B,H,T,D] bf16
// (q scaled by 0.125*log2e for exp2-softmax), v -> [B,H,D,T] bf16.
// MODE 1: fp32 output [M,N].
template <int MODE>
__global__ __launch_bounds__(256) void gemm128(
    const __bf16* __restrict__ A, const __bf16* __restrict__ Bt,
    const float* __restrict__ bias,
    __bf16* __restrict__ oq, __bf16* __restrict__ ok, __bf16* __restrict__ ov,
    float* __restrict__ of, int M, int N, int K) {
    __shared__ __align__(16) __bf16 As[128 * 64];
    __shared__ __align__(16) __bf16 Bs[128 * 64];
    const int tid = threadIdx.x;
    const int w = tid >> 6, lane = tid & 63;
    const int l15 = lane & 15, lg = lane >> 4;
    const int m0 = blockIdx.y * 128, n0 = blockIdx.x * 128;
    const int wr = w >> 1, wc = w & 1;

    const f32x4 zero4 = {0.f, 0.f, 0.f, 0.f};
    f32x4 acc[4][4];
#pragma unroll
    for (int m = 0; m < 4; ++m)
#pragma unroll
        for (int n = 0; n < 4; ++n) acc[m][n] = zero4;

    const char* Ab = (const char*)A;
    const char* Bb = (const char*)Bt;
    const size_t rowbytes = (size_t)K * 2;

    for (int kt = 0; kt < K; kt += 64) {
#pragma unroll
        for (int j = 0; j < 4; ++j) {
            int base = (w * 4 + j) * 1024;
            int d0 = base + lane * 16;
            int row = d0 >> 7;
            int colb = d0 & 127;
            int scolb = colb ^ ((row & 7) << 4);
            gload16(Ab + (size_t)(m0 + row) * rowbytes + (size_t)kt * 2 + scolb,
                    (char*)As + base);
            gload16(Bb + (size_t)(n0 + row) * rowbytes + (size_t)kt * 2 + scolb,
                    (char*)Bs + base);
        }
        __syncthreads();
#pragma unroll
        for (int kk = 0; kk < 2; ++kk) {
            bf16x8 af[4], bfr[4];
#pragma unroll
            for (int m = 0; m < 4; ++m) {
                int row = wr * 64 + m * 16 + l15;
                int colb = kk * 64 + lg * 16;
                af[m] = *(const bf16x8*)((const char*)As + row * 128 +
                                         (colb ^ ((row & 7) << 4)));
            }
#pragma unroll
            for (int n = 0; n < 4; ++n) {
                int row = wc * 64 + n * 16 + l15;
                int colb = kk * 64 + lg * 16;
                bfr[n] = *(const bf16x8*)((const char*)Bs + row * 128 +
                                          (colb ^ ((row & 7) << 4)));
            }
#pragma unroll
            for (int m = 0; m < 4; ++m)
#pragma unroll
                for (int n = 0; n < 4; ++n)
                    acc[m][n] = MFMA(af[m], bfr[n], acc[m][n]);
        }
        __syncthreads();
    }

    // epilogue. D layout: col = lane&15, row = (lane>>4)*4 + r  [verified m89/m91]
#pragma unroll
    for (int n = 0; n < 4; ++n) {
        int col = n0 + wc * 64 + n * 16 + l15;
        float bs = bias[col];
        if constexpr (MODE == 0) {
            int sec = col >> 10;          // 0=q 1=k 2=v
            int cc = col & 1023;
            int h = cc >> 6, d = cc & 63;
            if (sec == 2) {
                // V transposed: [B,H,D,T], pack 4 consecutive t per store
#pragma unroll
                for (int m = 0; m < 4; ++m) {
                    int rowb = m0 + wr * 64 + m * 16 + lg * 4;
                    int bb = rowb >> 11, t = rowb & 2047;
                    bf16x4 pk;
#pragma unroll
                    for (int r = 0; r < 4; ++r) pk[r] = (__bf16)(acc[m][n][r] + bs);
                    *(bf16x4*)&ov[((size_t)(bb * NH + h) * HD + d) * TT + t] = pk;
                }
            } else {
                __bf16* dst = (sec == 0) ? oq : ok;
                // fold softmax scale AND log2(e) into q so attn uses exp2
                float mult = (sec == 0) ? 0.125f * 1.44269504088896340736f : 1.0f;
#pragma unroll
                for (int m = 0; m < 4; ++m) {
                    int rowb = m0 + wr * 64 + m * 16 + lg * 4;
#pragma unroll
                    for (int r = 0; r < 4; ++r) {
                        int row = rowb + r;
                        int bb = row >> 11, t = row & 2047;
                        float val = (acc[m][n][r] + bs) * mult;
                        dst[((size_t)(bb * NH + h) * TT + t) * HD + d] = (__bf16)val;
                    }
                }
            }
        } else {
#pragma unroll
            for (int m = 0; m < 4; ++m) {
                int rowb = m0 + wr * 64 + m * 16 + lg * 4;
#pragma unroll
                for (int r = 0; r < 4; ++r) {
                    int row = rowb + r;
                    of[(size_t)row * N + col] = acc[m][n][r] + bs;
                }
            }
        }
    }
}

// ---------------- causal flash attention --------------------------------
// QTILE=64 (4 waves x 16 q-rows), KVBLK=64, paired q-tiles (qt, 31-qt):
// 512 uniform blocks of 33 steps. Swapped MFMA (S^T=mfma(K,Q)): softmax
// state per-lane scalar. 3-buffer K/V + counted vmcnt (T3/T4): prefetch
// stays in flight across raw s_barriers. XCD-grouped grid: the 16 blocks
// sharing a head's K/V land on one XCD's L2.
// q,k: [B,H,T,64] bf16 (q pre-scaled by 0.125*log2e). vt: [B,H,64,T] bf16.
__global__ __launch_bounds__(256) void attn_kernel(
    const __bf16* __restrict__ q, const __bf16* __restrict__ k,
    const __bf16* __restrict__ vt, __bf16* __restrict__ y) {
    __shared__ __align__(16) __bf16 Kb[3][64 * 64];   // [kv][d] 128B rows, XOR swz
    __shared__ __align__(16) __bf16 Vb[3][64 * 64];   // [d][kv] 128B rows, XOR swz
    __shared__ __align__(16) __bf16 Pl[4][16 * 68];   // per-wave P^T [q][k], 136B rows

    const int n = blockIdx.x;
    const int bh = (n & 7) * 4 + ((n >> 3) & 3);   // 4 heads per XCD slot
    const int qp = n >> 5;                          // 0..15 pair index
    const int tid = threadIdx.x, w = tid >> 6, lane = tid & 63;
    const int l15 = lane & 15, lg = lane >> 4;
    const char* kh = (const char*)(k + (size_t)bh * TT * HD);
    const char* vh = (const char*)(vt + (size_t)bh * HD * TT);
    const __bf16* qh = q + (size_t)bh * TT * HD;
    const int qtA = qp, qtB = 31 - qp;
    const int nA = qtA + 1;                         // ntot == 33 always

    const f32x4 zero4 = {0.f, 0.f, 0.f, 0.f};
    float mrun, lrun;
    f32x4 oacc[4];        // O^T: col=q=l15, row d = f*16 + lg*4 + r
    bf16x8 qf[2];
    int qbw = 0;

    auto stage = [&](int kvb, int buf) {
#pragma unroll
        for (int j = 0; j < 2; ++j) {
            int d0 = ((w * 2 + j) * 64 + lane) * 16;
            int row = d0 >> 7, colb = d0 & 127;
            int scolb = colb ^ ((row & 7) << 4);
            gload16(kh + (size_t)(kvb + row) * 128 + scolb, (char*)Kb[buf] + d0);
            gload16(vh + (size_t)row * (TT * 2) + (size_t)kvb * 2 + scolb,
                    (char*)Vb[buf] + d0);
        }
    };
    auto ktile = [&](int g) { return (g < nA ? g : g - nA) * 64; };

    auto initQ = [&](int qt) {
        qbw = qt * 64 + w * 16;
#pragma unroll
        for (int kk = 0; kk < 2; ++kk)
            qf[kk] = *(const bf16x8*)&qh[(size_t)(qbw + l15) * HD + kk * 32 + lg * 8];
        mrun = -1e30f; lrun = 0.f;
#pragma unroll
        for (int f = 0; f < 4; ++f) oacc[f] = zero4;
    };

    auto writeO = [&]() {
        const int b = bh >> 4, h = bh & 15;
        float inv = 1.0f / lrun;
#pragma unroll
        for (int f = 0; f < 4; ++f) {
            bf16x4 pk;
#pragma unroll
            for (int r = 0; r < 4; ++r) pk[r] = (__bf16)(oacc[f][r] * inv);
            *(bf16x4*)&y[(size_t)(b * TT + qbw + l15) * CC + h * 64 + f * 16 +
                         lg * 4] = pk;
        }
    };

    // prologue: fill pipeline 2 deep (4 loads/wave per stage)
    stage(ktile(0), 0);
    stage(ktile(1), 1);
    initQ(qtA);
    asm volatile("s_waitcnt vmcnt(4)" ::: "memory");   // tile 0 landed
    __builtin_amdgcn_sched_barrier(0);
    __builtin_amdgcn_s_barrier();

    for (int g = 0; g < 33; ++g) {
        const int cur = g % 3;
        if (g + 2 < 33) stage(ktile(g + 2), (g + 2) % 3);
        const int kb = ktile(g);

        // ---- S^T = K Q^T ---- (col=q=l15, row k = kf*16 + lg*4 + r)
        f32x4 s[4];
#pragma unroll
        for (int kf = 0; kf < 4; ++kf) s[kf] = zero4;
        __builtin_amdgcn_s_setprio(1);
#pragma unroll
        for (int kf = 0; kf < 4; ++kf) {
            int krow = kf * 16 + l15;
            const char* kr = (const char*)Kb[cur] + krow * 128;
            bf16x8 k0 = *(const bf16x8*)(kr + ((lg * 16) ^ ((krow & 7) << 4)));
            bf16x8 k1 = *(const bf16x8*)(kr + ((64 + lg * 16) ^ ((krow & 7) << 4)));
            s[kf] = MFMA(k0, qf[0], s[kf]);
            s[kf] = MFMA(k1, qf[1], s[kf]);
        }
        __builtin_amdgcn_s_setprio(0);
        // mask iff max k (kb+63) can exceed wave's MIN q (qbw)
        const int qq = qbw + l15;
        if (kb + 63 > qbw) {
#pragma unroll
            for (int kf = 0; kf < 4; ++kf)
#pragma unroll
                for (int r = 0; r < 4; ++r) {
                    int kk_ = kb + kf * 16 + lg * 4 + r;
                    if (kk_ > qq) s[kf][r] = -1e30f;
                }
        }
        // ---- online softmax (per-lane q; in-lane k-reduce + 2 shfl) ----
        f32x4 m01, m23;
#pragma unroll
        for (int r = 0; r < 4; ++r) {
            m01[r] = fmaxf(s[0][r], s[1][r]);
            m23[r] = fmaxf(s[2][r], s[3][r]);
        }
        float m_ = fmaxf(fmaxf(fmaxf(m01[0], m01[1]), fmaxf(m01[2], m01[3])),
                         fmaxf(fmaxf(m23[0], m23[1]), fmaxf(m23[2], m23[3])));
        m_ = fmaxf(m_, __shfl_xor(m_, 16));
        m_ = fmaxf(m_, __shfl_xor(m_, 32));
        float mn = fmaxf(mrun, m_);
        float fac = exp2f(mrun - mn);
        mrun = mn;
        float ss = 0.f;
#pragma unroll
        for (int kf = 0; kf < 4; ++kf)
#pragma unroll
            for (int r = 0; r < 4; ++r) {
                float p = exp2f(s[kf][r] - mn);
                s[kf][r] = p;
                ss += p;
            }
        ss += __shfl_xor(ss, 16);
        ss += __shfl_xor(ss, 32);
        lrun = lrun * fac + ss;
#pragma unroll
        for (int f = 0; f < 4; ++f)
#pragma unroll
            for (int r = 0; r < 4; ++r) oacc[f][r] *= fac;
        // ---- P^T -> LDS (packed b64; 136B rows = proven 0-conflict reads) ----
#pragma unroll
        for (int kf = 0; kf < 4; ++kf) {
            bf16x4 pk;
#pragma unroll
            for (int r = 0; r < 4; ++r) pk[r] = (__bf16)s[kf][r];
            *(bf16x4*)&Pl[w][l15 * 68 + kf * 16 + lg * 4] = pk;
        }
        // ---- O^T += V^T P ---- (A=V^T rows d=l15, B=P^T cols q=l15)
        __builtin_amdgcn_s_setprio(1);
#pragma unroll
        for (int kq = 0; kq < 2; ++kq) {
            bf16x8 pfrag = *(const bf16x8*)&Pl[w][l15 * 68 + kq * 32 + lg * 8];
#pragma unroll
            for (int f = 0; f < 4; ++f) {
                int vrow = f * 16 + l15;
                bf16x8 vf = *(const bf16x8*)((const char*)Vb[cur] + vrow * 128 +
                                ((kq * 64 + lg * 16) ^ ((vrow & 7) << 4)));
                oacc[f] = MFMA(vf, pfrag, oacc[f]);
            }
        }
        __builtin_amdgcn_s_setprio(0);

        // ---- counted-vmcnt pipeline sync: tile g+1 stays resident, g+2 in flight
        if (g + 1 < 33) {
            if (g + 2 < 33) asm volatile("s_waitcnt vmcnt(4)" ::: "memory");
            else            asm volatile("s_waitcnt vmcnt(0)" ::: "memory");
            __builtin_amdgcn_sched_barrier(0);
        }
        __builtin_amdgcn_s_barrier();
        if (g == nA - 1) { writeO(); initQ(qtB); }
    }
    writeO();
}

extern "C" void kernel_launch(void* const* d_in, const int* in_sizes, int n_in,
                              void* d_out, int out_size, void* d_ws, size_t ws_size,
                              hipStream_t stream) {
    const float* x      = (const float*)d_in[0];
    const float* w_attn = (const float*)d_in[1];
    const float* b_attn = (const float*)d_in[2];
    const float* w_proj = (const float*)d_in[3];
    const float* b_proj = (const float*)d_in[4];
    float* out = (float*)d_out;

    char* ws = (char*)d_ws;
    size_t off = 0;
    auto alloc = [&](size_t bytes) {
        char* p = ws + off;
        off += (bytes + 255) & ~(size_t)255;
        return p;
    };
    __bf16* xb   = (__bf16*)alloc((size_t)BT * CC * 2);
    __bf16* watb = (__bf16*)alloc((size_t)3 * CC * CC * 2);
    __bf16* wptb = (__bf16*)alloc((size_t)CC * CC * 2);
    __bf16* qb   = (__bf16*)alloc((size_t)BT * CC * 2);
    __bf16* kbuf = (__bf16*)alloc((size_t)BT * CC * 2);
    __bf16* vtb  = (__bf16*)alloc((size_t)BT * CC * 2);  // [B,H,D,T]
    __bf16* yb   = (__bf16*)alloc((size_t)BT * CC * 2);

    conv_f32_bf16<<<1024, 256, 0, stream>>>(x, xb, BT * CC / 4);
    transpose_f32_bf16<<<dim3(3 * CC / 32, CC / 32), dim3(32, 8), 0, stream>>>(
        w_attn, watb, CC, 3 * CC);
    transpose_f32_bf16<<<dim3(CC / 32, CC / 32), dim3(32, 8), 0, stream>>>(
        w_proj, wptb, CC, CC);

    gemm128<0><<<dim3(3 * CC / 128, BT / 128), 256, 0, stream>>>(
        xb, watb, b_attn, qb, kbuf, vtb, nullptr, BT, 3 * CC, CC);

    attn_kernel<<<512, 256, 0, stream>>>(qb, kbuf, vtb, yb);

    gemm128<1><<<dim3(CC / 128, BT / 128), 256, 0, stream>>>(
        yb, wptb, b_proj, nullptr, nullptr, nullptr, out, BT, CC, CC);
}

// Round 8
// 117.221 us; speedup vs baseline: 1.3919x; 1.0527x over previous
//
#include <hip/hip_runtime.h>
#include <hip/hip_bf16.h>
#include <stdint.h>

// Problem constants: B=2, T=2048, C=1024, H=16, D=64
#define TT 2048
#define CC 1024
#define NH 16
#define HD 64
#define BT 4096          // B*T rows

typedef float f32x4 __attribute__((ext_vector_type(4)));
typedef __bf16 bf16x8 __attribute__((ext_vector_type(8)));
typedef __bf16 bf16x4 __attribute__((ext_vector_type(4)));

#define MFMA(a, b, c) __builtin_amdgcn_mfma_f32_16x16x32_bf16((a), (b), (c), 0, 0, 0)

__device__ __forceinline__ void gload16(const void* g, void* l) {
    __builtin_amdgcn_global_load_lds(
        (const __attribute__((address_space(1))) void*)g,
        (__attribute__((address_space(3))) void*)l,
        16, 0, 0);
}

// ---------------- fp32 -> bf16 convert (no transpose) ----------------
__global__ __launch_bounds__(256) void conv_f32_bf16(
    const float* __restrict__ in, __bf16* __restrict__ out, int n4) {
    int i = blockIdx.x * blockDim.x + threadIdx.x;
    int stride = gridDim.x * blockDim.x;
    for (; i < n4; i += stride) {
        float4 v = reinterpret_cast<const float4*>(in)[i];
        bf16x4 o;
        o.x = (__bf16)v.x; o.y = (__bf16)v.y; o.z = (__bf16)v.z; o.w = (__bf16)v.w;
        reinterpret_cast<bf16x4*>(out)[i] = o;
    }
}

// ---------------- fp32 [R][C] -> bf16 [C][R] transpose ----------------
__global__ __launch_bounds__(256) void transpose_f32_bf16(
    const float* __restrict__ in, __bf16* __restrict__ out, int R, int C) {
    __shared__ float tile[32][33];
    int c0 = blockIdx.x * 32, r0 = blockIdx.y * 32;
    int tx = threadIdx.x, ty = threadIdx.y;
#pragma unroll
    for (int j = 0; j < 32; j += 8)
        tile[ty + j][tx] = in[(size_t)(r0 + ty + j) * C + c0 + tx];
    __syncthreads();
#pragma unroll
    for (int j = 0; j < 32; j += 8)
        out[(size_t)(c0 + ty + j) * R + r0 + tx] = (__bf16)tile[tx][ty + j];
}

// ---------------- bf16 MFMA GEMM, 128x128 tile, BK=64 (m97 structure) ----
// C = A[M,K] * Bt[N,K]^T + bias. MODE 0: scatter q/k -> [B,H,T,D] bf16
// (q scaled by 0.125*log2e for exp2-softmax), v -> [B,H,D,T] bf16.
// MODE 1: fp32 output [M,N].
template <int MODE>
__global__ __launch_bounds__(256) void gemm128(
    const __bf16* __restrict__ A, const __bf16* __restrict__ Bt,
    const float* __restrict__ bias,
    __bf16* __restrict__ oq, __bf16* __restrict__ ok, __bf16* __restrict__ ov,
    float* __restrict__ of, int M, int N, int K) {
    __shared__ __align__(16) __bf16 As[128 * 64];
    __shared__ __align__(16) __bf16 Bs[128 * 64];
    const int tid = threadIdx.x;
    const int w = tid >> 6, lane = tid & 63;
    const int l15 = lane & 15, lg = lane >> 4;
    const int m0 = blockIdx.y * 128, n0 = blockIdx.x * 128;
    const int wr = w >> 1, wc = w & 1;

    const f32x4 zero4 = {0.f, 0.f, 0.f, 0.f};
    f32x4 acc[4][4];
#pragma unroll
    for (int m = 0; m < 4; ++m)
#pragma unroll
        for (int n = 0; n < 4; ++n) acc[m][n] = zero4;

    const char* Ab = (const char*)A;
    const char* Bb = (const char*)Bt;
    const size_t rowbytes = (size_t)K * 2;

    for (int kt = 0; kt < K; kt += 64) {
#pragma unroll
        for (int j = 0; j < 4; ++j) {
            int base = (w * 4 + j) * 1024;
            int d0 = base + lane * 16;
            int row = d0 >> 7;
            int colb = d0 & 127;
            int scolb = colb ^ ((row & 7) << 4);
            gload16(Ab + (size_t)(m0 + row) * rowbytes + (size_t)kt * 2 + scolb,
                    (char*)As + base);
            gload16(Bb + (size_t)(n0 + row) * rowbytes + (size_t)kt * 2 + scolb,
                    (char*)Bs + base);
        }
        __syncthreads();
#pragma unroll
        for (int kk = 0; kk < 2; ++kk) {
            bf16x8 af[4], bfr[4];
#pragma unroll
            for (int m = 0; m < 4; ++m) {
                int row = wr * 64 + m * 16 + l15;
                int colb = kk * 64 + lg * 16;
                af[m] = *(const bf16x8*)((const char*)As + row * 128 +
                                         (colb ^ ((row & 7) << 4)));
            }
#pragma unroll
            for (int n = 0; n < 4; ++n) {
                int row = wc * 64 + n * 16 + l15;
                int colb = kk * 64 + lg * 16;
                bfr[n] = *(const bf16x8*)((const char*)Bs + row * 128 +
                                          (colb ^ ((row & 7) << 4)));
            }
#pragma unroll
            for (int m = 0; m < 4; ++m)
#pragma unroll
                for (int n = 0; n < 4; ++n)
                    acc[m][n] = MFMA(af[m], bfr[n], acc[m][n]);
        }
        __syncthreads();
    }

    // epilogue. D layout: col = lane&15, row = (lane>>4)*4 + r  [verified m89/m91]
#pragma unroll
    for (int n = 0; n < 4; ++n) {
        int col = n0 + wc * 64 + n * 16 + l15;
        float bs = bias[col];
        if constexpr (MODE == 0) {
            int sec = col >> 10;          // 0=q 1=k 2=v
            int cc = col & 1023;
            int h = cc >> 6, d = cc & 63;
            if (sec == 2) {
                // V transposed: [B,H,D,T], pack 4 consecutive t per store
#pragma unroll
                for (int m = 0; m < 4; ++m) {
                    int rowb = m0 + wr * 64 + m * 16 + lg * 4;
                    int bb = rowb >> 11, t = rowb & 2047;
                    bf16x4 pk;
#pragma unroll
                    for (int r = 0; r < 4; ++r) pk[r] = (__bf16)(acc[m][n][r] + bs);
                    *(bf16x4*)&ov[((size_t)(bb * NH + h) * HD + d) * TT + t] = pk;
                }
            } else {
                __bf16* dst = (sec == 0) ? oq : ok;
                // fold softmax scale AND log2(e) into q so attn uses exp2
                float mult = (sec == 0) ? 0.125f * 1.44269504088896340736f : 1.0f;
#pragma unroll
                for (int m = 0; m < 4; ++m) {
                    int rowb = m0 + wr * 64 + m * 16 + lg * 4;
#pragma unroll
                    for (int r = 0; r < 4; ++r) {
                        int row = rowb + r;
                        int bb = row >> 11, t = row & 2047;
                        float val = (acc[m][n][r] + bs) * mult;
                        dst[((size_t)(bb * NH + h) * TT + t) * HD + d] = (__bf16)val;
                    }
                }
            }
        } else {
#pragma unroll
            for (int m = 0; m < 4; ++m) {
                int rowb = m0 + wr * 64 + m * 16 + lg * 4;
#pragma unroll
                for (int r = 0; r < 4; ++r) {
                    int row = rowb + r;
                    of[(size_t)row * N + col] = acc[m][n][r] + bs;
                }
            }
        }
    }
}

// ---------------- causal flash attention --------------------------------
// One q-tile (64 rows, 4 waves x 16) per block; 32 tiles x 32 heads = 1024
// blocks, heavy tiles dispatched first, 4 heads per XCD (L2-resident KV).
// 41.5KB LDS -> 3 resident blocks/CU (TLP to hide the softmax chain).
// Swapped MFMA (S^T=mfma(K,Q)): per-lane softmax state; lrun cross-lane sum
// deferred to epilogue; rescale skipped when the running max is unchanged.
// q,k: [B,H,T,64] bf16 (q pre-scaled by 0.125*log2e). vt: [B,H,64,T] bf16.
__global__ __launch_bounds__(256) void attn_kernel(
    const __bf16* __restrict__ q, const __bf16* __restrict__ k,
    const __bf16* __restrict__ vt, __bf16* __restrict__ y) {
    __shared__ __align__(16) __bf16 Kb[2][64 * 64];   // [kv][d] 128B rows, XOR swz
    __shared__ __align__(16) __bf16 Vb[2][64 * 64];   // [d][kv] 128B rows, XOR swz
    __shared__ __align__(16) __bf16 Pl[4][16 * 68];   // per-wave P^T [q][k], 136B rows

    const int n = blockIdx.x;
    const int qt = 31 - (n >> 5);                  // heavy q-tiles first
    const int bh = ((n & 7) << 2) | ((n >> 3) & 3);  // 4 heads per XCD slot
    const int tid = threadIdx.x, w = tid >> 6, lane = tid & 63;
    const int l15 = lane & 15, lg = lane >> 4;
    const char* kh = (const char*)(k + (size_t)bh * TT * HD);
    const char* vh = (const char*)(vt + (size_t)bh * HD * TT);
    const __bf16* qh = q + (size_t)bh * TT * HD;
    const int qbw = qt * 64 + w * 16;

    const f32x4 zero4 = {0.f, 0.f, 0.f, 0.f};
    float mrun = -1e30f, lrun = 0.f;   // lrun: per-lane partial (16 k each)
    f32x4 oacc[4];                     // O^T: col=q=l15, row d = f*16+lg*4+r
    bf16x8 qf[2];
#pragma unroll
    for (int f = 0; f < 4; ++f) oacc[f] = zero4;
#pragma unroll
    for (int kk = 0; kk < 2; ++kk)
        qf[kk] = *(const bf16x8*)&qh[(size_t)(qbw + l15) * HD + kk * 32 + lg * 8];

    auto stage = [&](int kvb, int buf) {
#pragma unroll
        for (int j = 0; j < 2; ++j) {
            int d0 = ((w * 2 + j) * 64 + lane) * 16;
            int row = d0 >> 7, colb = d0 & 127;
            int scolb = colb ^ ((row & 7) << 4);
            gload16(kh + (size_t)(kvb + row) * 128 + scolb, (char*)Kb[buf] + d0);
            gload16(vh + (size_t)row * (TT * 2) + (size_t)kvb * 2 + scolb,
                    (char*)Vb[buf] + d0);
        }
    };

    stage(0, 0);
    __syncthreads();

    for (int g = 0; g <= qt; ++g) {
        const int cur = g & 1;
        if (g < qt) stage((g + 1) * 64, cur ^ 1);
        const int kb = g * 64;

        // ---- S^T = K Q^T ---- (col=q=l15, row k = kf*16 + lg*4 + r)
        f32x4 s[4];
#pragma unroll
        for (int kf = 0; kf < 4; ++kf) s[kf] = zero4;
        __builtin_amdgcn_s_setprio(1);
#pragma unroll
        for (int kf = 0; kf < 4; ++kf) {
            int krow = kf * 16 + l15;
            const char* kr = (const char*)Kb[cur] + krow * 128;
            bf16x8 k0 = *(const bf16x8*)(kr + ((lg * 16) ^ ((krow & 7) << 4)));
            bf16x8 k1 = *(const bf16x8*)(kr + ((64 + lg * 16) ^ ((krow & 7) << 4)));
            s[kf] = MFMA(k0, qf[0], s[kf]);
            s[kf] = MFMA(k1, qf[1], s[kf]);
        }
        __builtin_amdgcn_s_setprio(0);
        // only the diagonal tile (g == qt) needs the causal mask
        if (g == qt) {
            const int qq = qbw + l15;
#pragma unroll
            for (int kf = 0; kf < 4; ++kf)
#pragma unroll
                for (int r = 0; r < 4; ++r) {
                    int kk_ = kb + kf * 16 + lg * 4 + r;
                    if (kk_ > qq) s[kf][r] = -1e30f;
                }
        }
        // ---- online softmax (per-lane q; in-lane tree + 2 shfl for max) ----
        f32x4 m01, m23;
#pragma unroll
        for (int r = 0; r < 4; ++r) {
            m01[r] = fmaxf(s[0][r], s[1][r]);
            m23[r] = fmaxf(s[2][r], s[3][r]);
        }
        float m_ = fmaxf(fmaxf(fmaxf(m01[0], m01[1]), fmaxf(m01[2], m01[3])),
                         fmaxf(fmaxf(m23[0], m23[1]), fmaxf(m23[2], m23[3])));
        m_ = fmaxf(m_, __shfl_xor(m_, 16));
        m_ = fmaxf(m_, __shfl_xor(m_, 32));
        if (!__all(m_ <= mrun)) {          // rescale only when max grows (exact)
            float mn = fmaxf(mrun, m_);
            float fac = exp2f(mrun - mn);
            mrun = mn;
            lrun *= fac;
#pragma unroll
            for (int f = 0; f < 4; ++f)
#pragma unroll
                for (int r = 0; r < 4; ++r) oacc[f][r] *= fac;
        }
        float ss = 0.f;
#pragma unroll
        for (int kf = 0; kf < 4; ++kf)
#pragma unroll
            for (int r = 0; r < 4; ++r) {
                float p = exp2f(s[kf][r] - mrun);
                s[kf][r] = p;
                ss += p;
            }
        lrun += ss;                        // cross-lane sum deferred to epilogue
        // ---- P^T -> LDS (packed b64; 136B rows, 0-conflict pattern) ----
#pragma unroll
        for (int kf = 0; kf < 4; ++kf) {
            bf16x4 pk;
#pragma unroll
            for (int r = 0; r < 4; ++r) pk[r] = (__bf16)s[kf][r];
            *(bf16x4*)&Pl[w][l15 * 68 + kf * 16 + lg * 4] = pk;
        }
        // ---- O^T += V^T P ---- (A=V^T rows d=l15, B=P^T cols q=l15)
        __builtin_amdgcn_s_setprio(1);
#pragma unroll
        for (int kq = 0; kq < 2; ++kq) {
            bf16x8 pfrag = *(const bf16x8*)&Pl[w][l15 * 68 + kq * 32 + lg * 8];
#pragma unroll
            for (int f = 0; f < 4; ++f) {
                int vrow = f * 16 + l15;
                bf16x8 vf = *(const bf16x8*)((const char*)Vb[cur] + vrow * 128 +
                                ((kq * 64 + lg * 16) ^ ((vrow & 7) << 4)));
                oacc[f] = MFMA(vf, pfrag, oacc[f]);
            }
        }
        __builtin_amdgcn_s_setprio(0);
        __syncthreads();
    }

    // epilogue: finish the lrun reduction across the 4 lg groups, write O^T
    lrun += __shfl_xor(lrun, 16);
    lrun += __shfl_xor(lrun, 32);
    const int b = bh >> 4, h = bh & 15;
    float inv = 1.0f / lrun;
#pragma unroll
    for (int f = 0; f < 4; ++f) {
        bf16x4 pk;
#pragma unroll
        for (int r = 0; r < 4; ++r) pk[r] = (__bf16)(oacc[f][r] * inv);
        *(bf16x4*)&y[(size_t)(b * TT + qbw + l15) * CC + h * 64 + f * 16 +
                     lg * 4] = pk;
    }
}

extern "C" void kernel_launch(void* const* d_in, const int* in_sizes, int n_in,
                              void* d_out, int out_size, void* d_ws, size_t ws_size,
                              hipStream_t stream) {
    const float* x      = (const float*)d_in[0];
    const float* w_attn = (const float*)d_in[1];
    const float* b_attn = (const float*)d_in[2];
    const float* w_proj = (const float*)d_in[3];
    const float* b_proj = (const float*)d_in[4];
    float* out = (float*)d_out;

    char* ws = (char*)d_ws;
    size_t off = 0;
    auto alloc = [&](size_t bytes) {
        char* p = ws + off;
        off += (bytes + 255) & ~(size_t)255;
        return p;
    };
    __bf16* xb   = (__bf16*)alloc((size_t)BT * CC * 2);
    __bf16* watb = (__bf16*)alloc((size_t)3 * CC * CC * 2);
    __bf16* wptb = (__bf16*)alloc((size_t)CC * CC * 2);
    __bf16* qb   = (__bf16*)alloc((size_t)BT * CC * 2);
    __bf16* kbuf = (__bf16*)alloc((size_t)BT * CC * 2);
    __bf16* vtb  = (__bf16*)alloc((size_t)BT * CC * 2);  // [B,H,D,T]
    __bf16* yb   = (__bf16*)alloc((size_t)BT * CC * 2);

    conv_f32_bf16<<<1024, 256, 0, stream>>>(x, xb, BT * CC / 4);
    transpose_f32_bf16<<<dim3(3 * CC / 32, CC / 32), dim3(32, 8), 0, stream>>>(
        w_attn, watb, CC, 3 * CC);
    transpose_f32_bf16<<<dim3(CC / 32, CC / 32), dim3(32, 8), 0, stream>>>(
        w_proj, wptb, CC, CC);

    gemm128<0><<<dim3(3 * CC / 128, BT / 128), 256, 0, stream>>>(
        xb, watb, b_attn, qb, kbuf, vtb, nullptr, BT, 3 * CC, CC);

    attn_kernel<<<1024, 256, 0, stream>>>(qb, kbuf, vtb, yb);

    gemm128<1><<<dim3(CC / 128, BT / 128), 256, 0, stream>>>(
        yb, wptb, b_proj, nullptr, nullptr, nullptr, out, BT, CC, CC);
}